// Round 1
// baseline (2686.392 us; speedup 1.0000x reference)
//
#include <hip/hip_runtime.h>
#include <hip/hip_bf16.h>
#include <cstdint>

#define NBATCH   16
#define NPIX     49152
#define NBUCKETS 8
#define C_IN     16
#define GRIDSZ   (NBATCH * NPIX * NBUCKETS)   // 6,291,456 cells
#define ROWS     (NBATCH * NPIX)              // 786,432 output rows
#define PROJ_IN  136
#define PROJ_MID 128
#define OUT_DIM  64
#define LN_EPS   1e-5f

// ---------- helpers ----------
__device__ __forceinline__ float rdlane(float v, int lane) {
    return __uint_as_float(__builtin_amdgcn_readlane(__float_as_uint(v), lane));
}
__device__ __forceinline__ uint32_t bf16_rn(float f) {
    uint32_t u = __float_as_uint(f);
    return (u + 0x7fffu + ((u >> 16) & 1u)) >> 16;
}
__device__ __forceinline__ uint32_t pack_bf16x2(float lo, float hi) {
    return bf16_rn(lo) | (bf16_rn(hi) << 16);
}

// ---------- kernel 1: scatter-add (4 threads per point) ----------
__global__ void scatter_kernel(const float* __restrict__ x,
                               const int* __restrict__ bidx,
                               const int* __restrict__ pix,
                               const int* __restrict__ bkt,
                               float* __restrict__ sums,
                               float* __restrict__ counts,
                               int npoints) {
    int tid = blockIdx.x * blockDim.x + threadIdx.x;
    int i = tid >> 2;
    if (i >= npoints) return;
    int c4 = (tid & 3) * 4;
    int flat = (bidx[i] * NPIX + pix[i]) * NBUCKETS + bkt[i];
    const float4 v = *(const float4*)(x + (size_t)i * C_IN + c4);
    float* dst = sums + (size_t)flat * C_IN + c4;
    unsafeAtomicAdd(dst + 0, v.x);
    unsafeAtomicAdd(dst + 1, v.y);
    unsafeAtomicAdd(dst + 2, v.z);
    unsafeAtomicAdd(dst + 3, v.w);
    if ((tid & 3) == 0) unsafeAtomicAdd(counts + flat, 1.0f);
}

// ---------- kernel 2: fused mean -> proj1 -> LN -> SiLU -> proj2 ----------
// One wave processes 8 rows per iteration.
// Lane l: r8 = l>>3 (row within group), c = l&7 (bucket / k-group).
// Lane l holds inputs k = c*16 + t (t=0..15, means) and k=128+c (presence).
__global__ __launch_bounds__(256) void fused_proj_kernel(
    const float* __restrict__ sums, const float* __restrict__ counts,
    const float* __restrict__ W1, const float* __restrict__ b1,
    const float* __restrict__ gamma, const float* __restrict__ beta,
    const float* __restrict__ W2, const float* __restrict__ b2,
    float* __restrict__ out) {

    __shared__ uint32_t sW1p[PROJ_IN * 64];  // (W1[k][j], W1[k][j+64]) bf16x2 : 34816 B
    __shared__ uint32_t sW2p[64 * 64];       // (W2[2q][i], W2[2q+1][i]) bf16x2: 16384 B

    const int tid = threadIdx.x;
    // stage weights (bf16 round-to-nearest)
    for (int idx = tid; idx < PROJ_IN * 64; idx += 256) {
        int k = idx >> 6, j = idx & 63;
        sW1p[idx] = pack_bf16x2(W1[k * PROJ_MID + j], W1[k * PROJ_MID + j + 64]);
    }
    for (int idx = tid; idx < 64 * 64; idx += 256) {
        int q = idx >> 6, i = idx & 63;
        sW2p[idx] = pack_bf16x2(W2[(2 * q) * OUT_DIM + i], W2[(2 * q + 1) * OUT_DIM + i]);
    }

    const int lane = tid & 63;
    const float b1a = b1[lane],    b1b = b1[lane + 64];
    const float ga  = gamma[lane], gb  = gamma[lane + 64];
    const float bea = beta[lane],  beb = beta[lane + 64];
    const float b2i = b2[lane];
    __syncthreads();

    const int wave   = blockIdx.x * 4 + (tid >> 6);
    const int nwaves = gridDim.x * 4;
    const int c  = lane & 7;
    const int r8 = lane >> 3;

    for (int g = wave; g < ROWS / 8; g += nwaves) {
        const int row = g * 8 + r8;
        const float* srow = sums + (size_t)row * PROJ_MID + c * 16;
        float cnt = counts[row * NBUCKETS + c];
        float rcp = (cnt > 0.f) ? (1.0f / cnt) : 0.f;

        float inreg[17];
        #pragma unroll
        for (int u = 0; u < 4; ++u) {
            float4 q = *(const float4*)(srow + 4 * u);
            inreg[4 * u + 0] = q.x * rcp;
            inreg[4 * u + 1] = q.y * rcp;
            inreg[4 * u + 2] = q.z * rcp;
            inreg[4 * u + 3] = q.w * rcp;
        }
        inreg[16] = (cnt > 0.f) ? 1.0f : 0.0f;

        // ---- GEMM1: h[r][j], h[r][j+64] ----
        float acc0[8], acc1[8];
        #pragma unroll
        for (int r = 0; r < 8; ++r) { acc0[r] = 0.f; acc1[r] = 0.f; }

        #pragma unroll
        for (int t = 0; t < 17; ++t) {
            #pragma unroll 2
            for (int cc = 0; cc < 8; ++cc) {
                const int k = (t < 16) ? (cc * 16 + t) : (128 + cc);
                uint32_t wp = sW1p[k * 64 + lane];
                float w0 = __uint_as_float(wp << 16);
                float w1 = __uint_as_float(wp & 0xffff0000u);
                #pragma unroll
                for (int r = 0; r < 8; ++r) {
                    float s = rdlane(inreg[t], r * 8 + cc);
                    acc0[r] = fmaf(s, w0, acc0[r]);
                    acc1[r] = fmaf(s, w1, acc1[r]);
                }
            }
        }

        // ---- bias + LayerNorm + SiLU ----
        float hm0[8], hm1[8];
        #pragma unroll
        for (int r = 0; r < 8; ++r) {
            float h0 = acc0[r] + b1a;
            float h1 = acc1[r] + b1b;
            float s1 = h0 + h1;
            float s2 = h0 * h0 + h1 * h1;
            #pragma unroll
            for (int m = 1; m < 64; m <<= 1) {
                s1 += __shfl_xor(s1, m, 64);
                s2 += __shfl_xor(s2, m, 64);
            }
            float mu  = s1 * (1.0f / 128.0f);
            float var = s2 * (1.0f / 128.0f) - mu * mu;
            float rs  = rsqrtf(var + LN_EPS);
            float z0 = (h0 - mu) * rs * ga + bea;
            float z1 = (h1 - mu) * rs * gb + beb;
            hm0[r] = z0 / (1.0f + __expf(-z0));   // SiLU
            hm1[r] = z1 / (1.0f + __expf(-z1));
        }

        // ---- GEMM2: out[r][i] = sum_k hn[r][k] * W2[k][i] ----
        float acc2[8];
        #pragma unroll
        for (int r = 0; r < 8; ++r) acc2[r] = 0.f;

        #pragma unroll
        for (int half = 0; half < 2; ++half) {
            #pragma unroll 2
            for (int k2 = 0; k2 < 32; ++k2) {
                uint32_t wp = sW2p[(half * 32 + k2) * 64 + lane];
                float w0 = __uint_as_float(wp << 16);
                float w1 = __uint_as_float(wp & 0xffff0000u);
                #pragma unroll
                for (int r = 0; r < 8; ++r) {
                    float sa = rdlane(half ? hm1[r] : hm0[r], 2 * k2);
                    float sb = rdlane(half ? hm1[r] : hm0[r], 2 * k2 + 1);
                    acc2[r] = fmaf(sa, w0, acc2[r]);
                    acc2[r] = fmaf(sb, w1, acc2[r]);
                }
            }
        }

        // ---- epilogue ----
        #pragma unroll
        for (int r = 0; r < 8; ++r) {
            out[(size_t)(g * 8 + r) * OUT_DIM + lane] = acc2[r] + b2i;
        }
    }
}

// ---------- launcher ----------
extern "C" void kernel_launch(void* const* d_in, const int* in_sizes, int n_in,
                              void* d_out, int out_size, void* d_ws, size_t ws_size,
                              hipStream_t stream) {
    const float* x    = (const float*)d_in[0];
    const int*   bidx = (const int*)d_in[1];
    const int*   pix  = (const int*)d_in[2];
    const int*   bkt  = (const int*)d_in[3];
    // d_in[4] = nbatch, d_in[5] = npix (device scalars; shapes are fixed constants)
    const float* W1   = (const float*)d_in[6];
    const float* b1   = (const float*)d_in[7];
    const float* gmm  = (const float*)d_in[8];
    const float* bet  = (const float*)d_in[9];
    const float* W2   = (const float*)d_in[10];
    const float* b2   = (const float*)d_in[11];
    float* out = (float*)d_out;

    const int npoints = in_sizes[0] / C_IN;   // 4,000,000

    float* sums   = (float*)d_ws;                       // GRIDSZ*16 floats
    float* counts = sums + (size_t)GRIDSZ * C_IN;       // GRIDSZ floats
    const size_t zero_bytes = ((size_t)GRIDSZ * C_IN + GRIDSZ) * sizeof(float);

    hipMemsetAsync(d_ws, 0, zero_bytes, stream);

    {
        int threads = npoints * 4;
        int block = 256;
        int grid = (threads + block - 1) / block;
        scatter_kernel<<<grid, block, 0, stream>>>(x, bidx, pix, bkt, sums, counts, npoints);
    }
    {
        fused_proj_kernel<<<768, 256, 0, stream>>>(sums, counts, W1, b1, gmm, bet, W2, b2, out);
    }
}

// Round 2
// 1740.059 us; speedup vs baseline: 1.5439x; 1.5439x over previous
//
#include <hip/hip_runtime.h>
#include <hip/hip_bf16.h>
#include <cstdint>

#define NBATCH   16
#define NPIX     49152
#define NBUCKETS 8
#define C_IN     16
#define GRIDSZ   (NBATCH * NPIX * NBUCKETS)   // 6,291,456 cells
#define ROWS     (NBATCH * NPIX)              // 786,432 output rows
#define PROJ_IN  136
#define PROJ_MID 128
#define OUT_DIM  64
#define LN_EPS   1e-5f

typedef __attribute__((ext_vector_type(8))) short bf16x8;
typedef __attribute__((ext_vector_type(4))) float f32x4;
typedef __attribute__((ext_vector_type(4))) int   i32x4;

union FragU { i32x4 i; bf16x8 b; };

__device__ __forceinline__ uint32_t bf16_rn(float f) {
    uint32_t u = __float_as_uint(f);
    return (u + 0x7fffu + ((u >> 16) & 1u)) >> 16;
}
__device__ __forceinline__ uint32_t pack_bf16x2(float lo, float hi) {
    return bf16_rn(lo) | (bf16_rn(hi) << 16);
}

// ---------- kernel 1: scatter-add (4 threads per point) ----------
__global__ void scatter_kernel(const float* __restrict__ x,
                               const int* __restrict__ bidx,
                               const int* __restrict__ pix,
                               const int* __restrict__ bkt,
                               float* __restrict__ sums,
                               float* __restrict__ counts,
                               int npoints) {
    int tid = blockIdx.x * blockDim.x + threadIdx.x;
    int i = tid >> 2;
    if (i >= npoints) return;
    int c4 = (tid & 3) * 4;
    int flat = (bidx[i] * NPIX + pix[i]) * NBUCKETS + bkt[i];
    const float4 v = *(const float4*)(x + (size_t)i * C_IN + c4);
    float* dst = sums + (size_t)flat * C_IN + c4;
    unsafeAtomicAdd(dst + 0, v.x);
    unsafeAtomicAdd(dst + 1, v.y);
    unsafeAtomicAdd(dst + 2, v.z);
    unsafeAtomicAdd(dst + 3, v.w);
    if ((tid & 3) == 0) unsafeAtomicAdd(counts + flat, 1.0f);
}

// ---------- kernel 2: MFMA fused mean -> proj1 -> LN -> SiLU -> proj2 ----------
// One wave per 16-row tile; block = 4 waves = 64 rows per iteration.
// mfma_f32_16x16x32_bf16:  A[m=lane&15][k=(lane>>4)*8+i]
//                          B[k=(lane>>4)*8+i][n=lane&15]
//                          D[row=(lane>>4)*4+reg][col=lane&15]
__global__ __launch_bounds__(256, 2) void fused_proj_kernel(
    const float* __restrict__ sums, const float* __restrict__ counts,
    const float* __restrict__ W1, const float* __restrict__ b1,
    const float* __restrict__ gamma, const float* __restrict__ beta,
    const float* __restrict__ W2, const float* __restrict__ b2,
    float* __restrict__ out) {

    // W1 B-frags: ntile j in [0,8), kstep t in [0,5) (K padded 136->160), lane l.
    // slot = (j*5+t)*64+l, 4 uint32 (8 bf16) each.
    __shared__ uint32_t sW1[8 * 5 * 64 * 4];   // 40960 B
    // W2 B-frags: ntile j2 in [0,4), kstep t2 in [0,4).
    __shared__ uint32_t sW2[4 * 4 * 64 * 4];   // 16384 B
    // per-wave h roundtrip buffer: 16 rows x 136 bf16 (stride 136 = 272 B, 16B-aligned)
    __shared__ uint16_t hbuf[4][16 * 136];     // 17408 B

    const int tid = threadIdx.x;

    // ---- stage W1 fragments ----
    for (int idx = tid; idx < 8 * 5 * 64; idx += 256) {
        int j = idx / 320, rem = idx % 320;
        int t = rem / 64, l = rem % 64;
        int qq = l >> 4, cc = l & 15;
        int n = j * 16 + cc;
        i32x4 w;
        #pragma unroll
        for (int p = 0; p < 4; ++p) {
            int k0 = t * 32 + qq * 8 + 2 * p;
            float f0 = (k0 < PROJ_IN) ? W1[k0 * PROJ_MID + n] : 0.f;
            float f1 = (k0 + 1 < PROJ_IN) ? W1[(k0 + 1) * PROJ_MID + n] : 0.f;
            w[p] = (int)pack_bf16x2(f0, f1);
        }
        *(i32x4*)&sW1[idx * 4] = w;
    }
    // ---- stage W2 fragments ----
    for (int idx = tid; idx < 4 * 4 * 64; idx += 256) {
        int j2 = idx / 256, rem = idx % 256;
        int t2 = rem / 64, l = rem % 64;
        int qq = l >> 4, cc = l & 15;
        int n = j2 * 16 + cc;
        i32x4 w;
        #pragma unroll
        for (int p = 0; p < 4; ++p) {
            int k0 = t2 * 32 + qq * 8 + 2 * p;
            w[p] = (int)pack_bf16x2(W2[k0 * OUT_DIM + n], W2[(k0 + 1) * OUT_DIM + n]);
        }
        *(i32x4*)&sW2[idx * 4] = w;
    }

    const int lane = tid & 63;
    const int wv   = tid >> 6;
    const int q    = lane >> 4;
    const int c    = lane & 15;

    // per-lane epilogue constants (col = 16j + c)
    float b1v[8], gav[8], bev[8], b2v[4];
    #pragma unroll
    for (int j = 0; j < 8; ++j) {
        b1v[j] = b1[16 * j + c];
        gav[j] = gamma[16 * j + c];
        bev[j] = beta[16 * j + c];
    }
    #pragma unroll
    for (int j2 = 0; j2 < 4; ++j2) b2v[j2] = b2[16 * j2 + c];

    __syncthreads();

    uint16_t* hb = hbuf[wv];

    for (int grp = blockIdx.x; grp < ROWS / 64; grp += gridDim.x) {
        const int rowbase = grp * 64 + wv * 16;
        const int myrow   = rowbase + c;          // row for A-frag loads (m = lane&15)

        // counts row (8 floats, 32B, aligned)
        const float4 cn0 = *(const float4*)(counts + (size_t)myrow * 8);
        const float4 cn1 = *(const float4*)(counts + (size_t)myrow * 8 + 4);
        const float cns[8] = {cn0.x, cn0.y, cn0.z, cn0.w, cn1.x, cn1.y, cn1.z, cn1.w};

        // ---- build A fragments (means in bf16) ----
        FragU afrag[5];
        #pragma unroll
        for (int t = 0; t < 4; ++t) {
            const float* sp = sums + (size_t)myrow * 128 + t * 32 + q * 8;
            float4 s0 = *(const float4*)sp;
            float4 s1 = *(const float4*)(sp + 4);
            float cnt = (q & 2) ? cns[2 * t + 1] : cns[2 * t];
            float rcp = (cnt > 0.f) ? (1.0f / cnt) : 0.f;
            afrag[t].i[0] = (int)pack_bf16x2(s0.x * rcp, s0.y * rcp);
            afrag[t].i[1] = (int)pack_bf16x2(s0.z * rcp, s0.w * rcp);
            afrag[t].i[2] = (int)pack_bf16x2(s1.x * rcp, s1.y * rcp);
            afrag[t].i[3] = (int)pack_bf16x2(s1.z * rcp, s1.w * rcp);
        }
        // t=4: presence (k=128..135) only valid in q==0 lanes, zero elsewhere
        #pragma unroll
        for (int p = 0; p < 4; ++p) {
            uint32_t lo = (q == 0 && cns[2 * p]     > 0.f) ? 0x3F80u : 0u;
            uint32_t hi = (q == 0 && cns[2 * p + 1] > 0.f) ? 0x3F80u : 0u;
            afrag[4].i[p] = (int)(lo | (hi << 16));
        }

        // ---- GEMM1: h = A @ W1 ----
        f32x4 acc[8];
        #pragma unroll
        for (int j = 0; j < 8; ++j) acc[j] = (f32x4){0.f, 0.f, 0.f, 0.f};
        #pragma unroll
        for (int j = 0; j < 8; ++j) {
            #pragma unroll
            for (int t = 0; t < 5; ++t) {
                FragU w;
                w.i = *(const i32x4*)&sW1[((j * 5 + t) * 64 + lane) * 4];
                acc[j] = __builtin_amdgcn_mfma_f32_16x16x32_bf16(afrag[t].b, w.b, acc[j], 0, 0, 0);
            }
        }

        // ---- bias + LayerNorm + SiLU, write normalized h (bf16) to LDS ----
        #pragma unroll
        for (int r = 0; r < 3 + 1; ++r) {
            float h[8];
            float s1 = 0.f, s2 = 0.f;
            #pragma unroll
            for (int j = 0; j < 8; ++j) {
                h[j] = acc[j][r] + b1v[j];
                s1 += h[j];
                s2 += h[j] * h[j];
            }
            #pragma unroll
            for (int m = 1; m < 16; m <<= 1) {
                s1 += __shfl_xor(s1, m, 64);
                s2 += __shfl_xor(s2, m, 64);
            }
            float mu  = s1 * (1.0f / 128.0f);
            float var = s2 * (1.0f / 128.0f) - mu * mu;
            float rs  = rsqrtf(var + LN_EPS);
            int   row = q * 4 + r;
            #pragma unroll
            for (int j = 0; j < 8; ++j) {
                float z  = (h[j] - mu) * rs * gav[j] + bev[j];
                float sl = z / (1.0f + __expf(-z));
                hb[row * 136 + 16 * j + c] = (uint16_t)bf16_rn(sl);
            }
        }

        // ---- GEMM2: out = hn @ W2 (A2 from LDS roundtrip) ----
        FragU a2[4];
        #pragma unroll
        for (int t2 = 0; t2 < 4; ++t2) {
            a2[t2].i = *(const i32x4*)&((const uint32_t*)hb)[(c * 136 + t2 * 32 + q * 8) / 2];
        }
        f32x4 acc2[4];
        #pragma unroll
        for (int j2 = 0; j2 < 4; ++j2) acc2[j2] = (f32x4){0.f, 0.f, 0.f, 0.f};
        #pragma unroll
        for (int j2 = 0; j2 < 4; ++j2) {
            #pragma unroll
            for (int t2 = 0; t2 < 4; ++t2) {
                FragU w;
                w.i = *(const i32x4*)&sW2[((j2 * 4 + t2) * 64 + lane) * 4];
                acc2[j2] = __builtin_amdgcn_mfma_f32_16x16x32_bf16(a2[t2].b, w.b, acc2[j2], 0, 0, 0);
            }
        }

        // ---- epilogue: bias + store ----
        #pragma unroll
        for (int j2 = 0; j2 < 4; ++j2) {
            #pragma unroll
            for (int r = 0; r < 4; ++r) {
                out[(size_t)(rowbase + q * 4 + r) * OUT_DIM + 16 * j2 + c] = acc2[j2][r] + b2v[j2];
            }
        }
    }
}

// ---------- launcher ----------
extern "C" void kernel_launch(void* const* d_in, const int* in_sizes, int n_in,
                              void* d_out, int out_size, void* d_ws, size_t ws_size,
                              hipStream_t stream) {
    const float* x    = (const float*)d_in[0];
    const int*   bidx = (const int*)d_in[1];
    const int*   pix  = (const int*)d_in[2];
    const int*   bkt  = (const int*)d_in[3];
    const float* W1   = (const float*)d_in[6];
    const float* b1   = (const float*)d_in[7];
    const float* gmm  = (const float*)d_in[8];
    const float* bet  = (const float*)d_in[9];
    const float* W2   = (const float*)d_in[10];
    const float* b2   = (const float*)d_in[11];
    float* out = (float*)d_out;

    const int npoints = in_sizes[0] / C_IN;   // 4,000,000

    float* sums   = (float*)d_ws;                       // GRIDSZ*16 floats
    float* counts = sums + (size_t)GRIDSZ * C_IN;       // GRIDSZ floats
    const size_t zero_bytes = ((size_t)GRIDSZ * C_IN + GRIDSZ) * sizeof(float);

    hipMemsetAsync(d_ws, 0, zero_bytes, stream);

    {
        int threads = npoints * 4;
        int block = 256;
        int grid = (threads + block - 1) / block;
        scatter_kernel<<<grid, block, 0, stream>>>(x, bidx, pix, bkt, sums, counts, npoints);
    }
    {
        fused_proj_kernel<<<512, 256, 0, stream>>>(sums, counts, W1, b1, gmm, bet, W2, b2, out);
    }
}